// Round 4
// baseline (1037.404 us; speedup 1.0000x reference)
//
#include <hip/hip_runtime.h>
#include <hip/hip_bf16.h>
#include <cfloat>

#define Nn 2048
#define KK 20
#define BB 8
#define SLOPE 0.2f
#define NCH 32   // partial chunks in global conv (8 nblk x 4 waves)

typedef __bf16 bf16x8 __attribute__((ext_vector_type(8)));
typedef float f32x4 __attribute__((ext_vector_type(4)));

__device__ __forceinline__ unsigned short bfbits(__hip_bfloat16 h) {
    unsigned short us;
    __builtin_memcpy(&us, &h, 2);
    return us;
}

// ---------------- weight stack: Wstk[c][o] = W[o][c]; Wstk[c][Co+o] = W[o][C+c]-W[o][c]
__global__ void wstack_kernel(const float* __restrict__ W, float* __restrict__ Wstk,
                              int Co, int C) {
    int i = blockIdx.x * 256 + threadIdx.x;
    if (i < Co * C) {
        int o = i / C, c = i - o * C;
        float a = W[(long)o * 2 * C + c];
        float bb = W[(long)o * 2 * C + C + c];
        Wstk[(long)c * 2 * Co + o] = a;
        Wstk[(long)c * 2 * Co + Co + o] = bb - a;
    }
}

// ---------------- fp32 -> bf16 copy ----------------
__global__ void tobf16_kernel(const float* __restrict__ A, __hip_bfloat16* __restrict__ B,
                              int n) {
    int i = blockIdx.x * 256 + threadIdx.x;
    if (i < n) B[i] = __float2bfloat16(A[i]);
}

// ---------------- stage-1 split prep: x[b][3][n] -> hi/lo [b][n][32] (zero-padded), sq ----
__global__ void split3_kernel(const float* __restrict__ x,
                              __hip_bfloat16* __restrict__ xh,
                              __hip_bfloat16* __restrict__ xl,
                              float* __restrict__ sq) {
    int i = blockIdx.x * 256 + threadIdx.x;   // b*Nn + n
    if (i >= BB * Nn) return;
    const float* xb = x + (long)(i >> 11) * 3 * Nn + (i & 2047);
    float v0 = xb[0], v1 = xb[Nn], v2 = xb[2 * Nn];
    sq[i] = v0 * v0 + v1 * v1 + v2 * v2;
    __hip_bfloat16 h0 = __float2bfloat16(v0), h1 = __float2bfloat16(v1), h2 = __float2bfloat16(v2);
    __hip_bfloat16 l0 = __float2bfloat16(v0 - __bfloat162float(h0));
    __hip_bfloat16 l1 = __float2bfloat16(v1 - __bfloat162float(h1));
    __hip_bfloat16 l2 = __float2bfloat16(v2 - __bfloat162float(h2));
    ushort4* hp = (ushort4*)(xh + (long)i * 32);
    ushort4* lp = (ushort4*)(xl + (long)i * 32);
    ushort4 z; z.x = 0; z.y = 0; z.z = 0; z.w = 0;
    ushort4 hw; hw.x = bfbits(h0); hw.y = bfbits(h1); hw.z = bfbits(h2); hw.w = 0;
    ushort4 lw; lw.x = bfbits(l0); lw.y = bfbits(l1); lw.z = bfbits(l2); lw.w = 0;
    hp[0] = hw; lp[0] = lw;
    #pragma unroll
    for (int q = 1; q < 8; ++q) { hp[q] = z; lp[q] = z; }
}

// order-preserving float-bits -> u32 map (works for negatives)
__device__ __forceinline__ unsigned fkey(float f) {
    unsigned u = __float_as_uint(f);
    return u ^ (((unsigned)((int)u >> 31)) | 0x80000000u);
}

// ---------------- KNN via MFMA Gram: 8 rows per block, 512 threads ----------------
// dist key = sq[j] - 2*G[n][j], G via split-bf16 (hi*hi + hi*lo + lo*hi) on matrix cores.
// A = 8 query rows (duplicated to 16), B = 16-col tiles of all 2048 points.
// Selection phase is the byte-identical proven ballot/lazy-top-2 machinery.
template<int C>
__global__ void __launch_bounds__(512)
knn_mfma(const __hip_bfloat16* __restrict__ xh, const __hip_bfloat16* __restrict__ xl,
         long nstride, long bstride, int coff,
         const float* __restrict__ sqv, int* __restrict__ idx) {
    constexpr int KS = C / 32;
    __shared__ unsigned dist[8][Nn];   // XOR-mapped float keys; 64 KB exactly
    const int tid = threadIdx.x;
    const int b  = blockIdx.x >> 8;         // Nn/8 = 256 blocks per b
    const int n0 = (blockIdx.x & 255) * 8;
    const int w = tid >> 6, lane = tid & 63;
    const int lm = lane & 15, quad = lane >> 4;

    const __hip_bfloat16* hB = xh + (long)b * bstride + coff;
    const __hip_bfloat16* lB = xl + (long)b * bstride + coff;
    const float* sqb = sqv + b * Nn;

    // A fragments: rows n0 + (lm&7); rows 8-15 duplicate rows 0-7 (ignored in D)
    bf16x8 ah[KS], al[KS];
    const long arow = (long)(n0 + (lm & 7)) * nstride;
    #pragma unroll
    for (int ks = 0; ks < KS; ++ks) {
        ah[ks] = *(const bf16x8*)(const void*)(hB + arow + ks * 32 + quad * 8);
        al[ks] = *(const bf16x8*)(const void*)(lB + arow + ks * 32 + quad * 8);
    }

    // wave w owns cols [w*256, w*256+256): 16 tiles of 16 cols
    #pragma unroll 2
    for (int t = 0; t < 16; ++t) {
        const int cb = w * 256 + t * 16;
        const long brow = (long)(cb + lm) * nstride;
        f32x4 acc = (f32x4){0.f, 0.f, 0.f, 0.f};
        #pragma unroll
        for (int ks = 0; ks < KS; ++ks) {
            bf16x8 bh = *(const bf16x8*)(const void*)(hB + brow + ks * 32 + quad * 8);
            bf16x8 bl = *(const bf16x8*)(const void*)(lB + brow + ks * 32 + quad * 8);
            acc = __builtin_amdgcn_mfma_f32_16x16x32_bf16(al[ks], bh, acc, 0, 0, 0);
            acc = __builtin_amdgcn_mfma_f32_16x16x32_bf16(ah[ks], bl, acc, 0, 0, 0);
            acc = __builtin_amdgcn_mfma_f32_16x16x32_bf16(ah[ks], bh, acc, 0, 0, 0);
        }
        // D mapping: col(j) = lane&15, row(m) = quad*4 + r; rows 0-7 are real queries
        float sqj = sqb[cb + lm];
        if (quad < 2) {
            #pragma unroll
            for (int r = 0; r < 4; ++r) {
                int m = quad * 4 + r;
                dist[m][cb + lm] = fkey(fmaf(-2.f, acc[r], sqj));
            }
        }
    }
    __syncthreads();

    // selection: wave w owns row w; lazy per-lane top-2 in registers.
    unsigned* drow = dist[w];
    int* outp = idx + ((long)b * Nn + n0 + w) * KK;

    auto scan2 = [&](unsigned long long& m1, unsigned long long& m2) {
        m1 = ~0ull; m2 = ~0ull;
        #pragma unroll
        for (int jj = 0; jj < 8; ++jj) {
            int j4 = (jj * 64 + lane) * 4;
            uint4 v = *(const uint4*)(drow + j4);
            unsigned long long kk0 = ((unsigned long long)v.x << 32) | (unsigned)(j4 + 0);
            unsigned long long kk1 = ((unsigned long long)v.y << 32) | (unsigned)(j4 + 1);
            unsigned long long kk2 = ((unsigned long long)v.z << 32) | (unsigned)(j4 + 2);
            unsigned long long kk3 = ((unsigned long long)v.w << 32) | (unsigned)(j4 + 3);
            unsigned long long hi;
            hi = kk0 > m1 ? kk0 : m1; m1 = kk0 < m1 ? kk0 : m1; m2 = hi < m2 ? hi : m2;
            hi = kk1 > m1 ? kk1 : m1; m1 = kk1 < m1 ? kk1 : m1; m2 = hi < m2 ? hi : m2;
            hi = kk2 > m1 ? kk2 : m1; m1 = kk2 < m1 ? kk2 : m1; m2 = hi < m2 ? hi : m2;
            hi = kk3 > m1 ? kk3 : m1; m1 = kk3 < m1 ? kk3 : m1; m2 = hi < m2 ? hi : m2;
        }
    };

    unsigned long long lm1, lm2;
    scan2(lm1, lm2);
    for (int k = 0; k < KK; ++k) {
        unsigned key = (unsigned)(lm1 >> 32);
        unsigned bk = key;
        #pragma unroll
        for (int s = 1; s < 64; s <<= 1) {
            unsigned ob = __shfl_xor(bk, s, 64);
            bk = ob < bk ? ob : bk;
        }
        unsigned long long winners = __ballot(key == bk);
        int wl = (int)(__ffsll((unsigned long long)winners) - 1);
        int bi = (int)__shfl((unsigned)lm1, wl, 64);   // winner's j (low 32 bits)
        if (lane == 0) outp[k] = bi;
        if (lane == wl) {
            drow[bi] = 0xFFFFFFFFu;  // consumed sentinel (keeps refills correct)
            if (lm2 != ~0ull) { lm1 = lm2; lm2 = ~0ull; }
            else scan2(lm1, lm2);    // rare: lane's 3rd+ win since last refill
        }
    }
}

// ---------------- projection GEMM: Z[m][0..2Co) = sum_c x[c][m] * Wstk[c][.] ----
template<int CIN, int CO2>
__global__ void __launch_bounds__(256)
proj_gemm(const float* __restrict__ x, long bst,
          const float* __restrict__ Wstk, float* __restrict__ Z) {
    const int tid = threadIdx.x;
    const int b  = blockIdx.x & 7;
    const int mt = (blockIdx.x >> 3) & 31;
    const int ot = blockIdx.x >> 8;
    const int mi = mt * 64 + (tid & 15) * 4;
    const int oj = ot * 64 + (tid >> 4) * 4;
    const float* xb = x + (long)b * bst + mi;

    float acc[4][4];
    #pragma unroll
    for (int r = 0; r < 4; ++r)
        #pragma unroll
        for (int j = 0; j < 4; ++j) acc[r][j] = 0.f;

    #pragma unroll 4
    for (int c = 0; c < CIN; ++c) {
        float4 xv = *(const float4*)(xb + (long)c * Nn);
        float4 wv = *(const float4*)(Wstk + (long)c * CO2 + oj);
        acc[0][0] += xv.x * wv.x; acc[0][1] += xv.x * wv.y; acc[0][2] += xv.x * wv.z; acc[0][3] += xv.x * wv.w;
        acc[1][0] += xv.y * wv.x; acc[1][1] += xv.y * wv.y; acc[1][2] += xv.y * wv.z; acc[1][3] += xv.y * wv.w;
        acc[2][0] += xv.z * wv.x; acc[2][1] += xv.z * wv.y; acc[2][2] += xv.z * wv.z; acc[2][3] += xv.z * wv.w;
        acc[3][0] += xv.w * wv.x; acc[3][1] += xv.w * wv.y; acc[3][2] += xv.w * wv.z; acc[3][3] += xv.w * wv.w;
    }
    float* Zb = Z + (long)b * 2048 * CO2;
    #pragma unroll
    for (int r = 0; r < 4; ++r) {
        float4 v = make_float4(acc[r][0], acc[r][1], acc[r][2], acc[r][3]);
        *(float4*)(Zb + (long)(mi + r) * CO2 + oj) = v;
    }
}

// ---------------- gather-max epilogue: also emits bf16 hi/lo n-major copies + slice norms ----
template<int CO, bool EMIT>
__global__ void __launch_bounds__(256)
gather_max(const float* __restrict__ Z, const int* __restrict__ idx,
           float* __restrict__ out, long obst,
           __hip_bfloat16* __restrict__ xbT, __hip_bfloat16* __restrict__ xbTlo,
           float* __restrict__ sqv, int coff) {
    constexpr int CO2 = 2 * CO;
    constexpr int VEC = CO / 64;
    __shared__ float tile[16][CO + 4];
    __shared__ int ji[16][KK];
    const int tid = threadIdx.x;
    const int b  = blockIdx.x & 7;
    const int n0 = (blockIdx.x >> 3) * 16;
    const float* Zb = Z + (long)b * 2048 * CO2;

    for (int t = tid; t < 16 * KK; t += 256) {
        int nn = t / KK, k = t - nn * KK;
        ji[nn][k] = idx[((long)b * Nn + n0 + nn) * KK + k];
    }
    __syncthreads();

    const int w = tid >> 6, lane = tid & 63;
    for (int i = 0; i < 4; ++i) {
        int nl = w * 4 + i, n = n0 + nl;
        float mx[VEC];
        #pragma unroll
        for (int v = 0; v < VEC; ++v) mx[v] = -FLT_MAX;
        for (int k = 0; k < KK; ++k) {
            int m = ji[nl][k];
            const float* zr = Zb + (long)m * CO2 + lane * VEC;
            if constexpr (VEC == 4) {
                float4 zv = *(const float4*)zr;
                mx[0] = fmaxf(mx[0], zv.x); mx[1] = fmaxf(mx[1], zv.y);
                mx[2] = fmaxf(mx[2], zv.z); mx[3] = fmaxf(mx[3], zv.w);
            } else if constexpr (VEC == 2) {
                float2 zv = *(const float2*)zr;
                mx[0] = fmaxf(mx[0], zv.x); mx[1] = fmaxf(mx[1], zv.y);
            } else {
                mx[0] = fmaxf(mx[0], zr[0]);
            }
        }
        const float* zc = Zb + (long)n * CO2 + CO + lane * VEC;
        __hip_bfloat16* xr = xbT + ((long)b * 2048 + n) * 512 + coff + lane * VEC;
        float y[VEC];
        if constexpr (VEC == 4) {
            float4 cv = *(const float4*)zc;
            y[0] = mx[0] + cv.x; y[1] = mx[1] + cv.y; y[2] = mx[2] + cv.z; y[3] = mx[3] + cv.w;
        } else if constexpr (VEC == 2) {
            float2 cv = *(const float2*)zc;
            y[0] = mx[0] + cv.x; y[1] = mx[1] + cv.y;
        } else {
            y[0] = mx[0] + zc[0];
        }
        unsigned short hb[VEC], lb[VEC];
        float s = 0.f;
        #pragma unroll
        for (int v = 0; v < VEC; ++v) {
            y[v] = y[v] > 0.f ? y[v] : SLOPE * y[v];
            tile[nl][lane * VEC + v] = y[v];
            __hip_bfloat16 h = __float2bfloat16(y[v]);
            hb[v] = bfbits(h);
            if constexpr (EMIT) {
                lb[v] = bfbits(__float2bfloat16(y[v] - __bfloat162float(h)));
                s += y[v] * y[v];
            }
        }
        if constexpr (VEC == 4) {
            ushort4 pk; pk.x = hb[0]; pk.y = hb[1]; pk.z = hb[2]; pk.w = hb[3];
            *(ushort4*)xr = pk;
        } else if constexpr (VEC == 2) {
            ushort2 pk; pk.x = hb[0]; pk.y = hb[1];
            *(ushort2*)xr = pk;
        } else {
            *(unsigned short*)xr = hb[0];
        }
        if constexpr (EMIT) {
            __hip_bfloat16* lr = xbTlo + ((long)b * 2048 + n) * 512 + coff + lane * VEC;
            if constexpr (VEC == 4) {
                ushort4 pk; pk.x = lb[0]; pk.y = lb[1]; pk.z = lb[2]; pk.w = lb[3];
                *(ushort4*)lr = pk;
            } else if constexpr (VEC == 2) {
                ushort2 pk; pk.x = lb[0]; pk.y = lb[1];
                *(ushort2*)lr = pk;
            } else {
                *(unsigned short*)lr = lb[0];
            }
            #pragma unroll
            for (int off = 1; off < 64; off <<= 1) s += __shfl_xor(s, off, 64);
            if (lane == 0) sqv[b * Nn + n] = s;
        }
    }
    __syncthreads();

    for (int r = tid; r < CO * 4; r += 256) {
        int o = r >> 2, q = r & 3;
        float4 vv;
        vv.x = tile[q * 4 + 0][o];
        vv.y = tile[q * 4 + 1][o];
        vv.z = tile[q * 4 + 2][o];
        vv.w = tile[q * 4 + 3][o];
        *(float4*)(out + (long)b * obst + (long)o * Nn + n0 + q * 4) = vv;
    }
}

// ---------------- Global conv via bf16 MFMA, fused max-over-n ----------------
__global__ void __launch_bounds__(256)
global_mfma(const __hip_bfloat16* __restrict__ Wgb,   // [1024][512]
            const __hip_bfloat16* __restrict__ xbT,   // [B][2048][512]
            float* __restrict__ partial) {            // [B][1024][NCH]
    const int tid = threadIdx.x;
    const int w = tid >> 6, lane = tid & 63;
    const int lm = lane & 15, quad = lane >> 4;
    const int b  = blockIdx.x >> 7;
    const int ot = (blockIdx.x >> 3) & 15;
    const int nb = blockIdx.x & 7;
    const int o0 = ot * 64;
    const int nbw = nb * 256 + w * 64;

    const __hip_bfloat16* Arow = Wgb + (long)(o0 + lm) * 512 + quad * 8;
    const __hip_bfloat16* Brow = xbT + ((long)b * 2048 + nbw + lm) * 512 + quad * 8;

    f32x4 acc[4][4];
    #pragma unroll
    for (int mt = 0; mt < 4; ++mt)
        #pragma unroll
        for (int nt = 0; nt < 4; ++nt)
            acc[mt][nt] = (f32x4){0.f, 0.f, 0.f, 0.f};

    #pragma unroll 2
    for (int kk = 0; kk < 512; kk += 32) {
        bf16x8 a[4], bb[4];
        #pragma unroll
        for (int mt = 0; mt < 4; ++mt)
            a[mt] = *(const bf16x8*)(const void*)(Arow + (long)mt * 16 * 512 + kk);
        #pragma unroll
        for (int nt = 0; nt < 4; ++nt)
            bb[nt] = *(const bf16x8*)(const void*)(Brow + (long)nt * 16 * 512 + kk);
        #pragma unroll
        for (int mt = 0; mt < 4; ++mt)
            #pragma unroll
            for (int nt = 0; nt < 4; ++nt)
                acc[mt][nt] = __builtin_amdgcn_mfma_f32_16x16x32_bf16(
                    a[mt], bb[nt], acc[mt][nt], 0, 0, 0);
    }

    // D mapping: col(n) = lane&15, row(m) = quad*4 + reg
    #pragma unroll
    for (int mt = 0; mt < 4; ++mt) {
        #pragma unroll
        for (int r = 0; r < 4; ++r) {
            float v = fmaxf(fmaxf(acc[mt][0][r], acc[mt][1][r]),
                            fmaxf(acc[mt][2][r], acc[mt][3][r]));
            #pragma unroll
            for (int s = 1; s < 16; s <<= 1)
                v = fmaxf(v, __shfl_xor(v, s, 16));
            if (lm == 0) {
                int o = o0 + mt * 16 + quad * 4 + r;
                partial[((long)b * 1024 + o) * NCH + nb * 4 + w] = v;
            }
        }
    }
}

// ---------------- final max over chunks + leaky ----------------
__global__ void gmax_kernel(const float* __restrict__ partial, float* __restrict__ out) {
    int i = blockIdx.x * 256 + threadIdx.x;   // 0..8191
    float m = -FLT_MAX;
    #pragma unroll
    for (int j = 0; j < NCH; ++j) m = fmaxf(m, partial[(long)i * NCH + j]);
    out[i] = m > 0.f ? m : SLOPE * m;
}

extern "C" void kernel_launch(void* const* d_in, const int* in_sizes, int n_in,
                              void* d_out, int out_size, void* d_ws, size_t ws_size,
                              hipStream_t stream) {
    const float* x  = (const float*)d_in[0];
    const float* W1 = (const float*)d_in[1];   // [64][6]
    const float* W2 = (const float*)d_in[2];   // [64][128]
    const float* W3 = (const float*)d_in[3];   // [128][128]
    const float* W4 = (const float*)d_in[4];   // [256][256]
    const float* Wg = (const float*)d_in[5];   // [1024][512]
    float* out = (float*)d_out;

    float* ws = (float*)d_ws;
    float* xcat = ws;                                       // 8*512*2048 f32
    int*   idxb = (int*)(xcat + (long)BB * 512 * Nn);       // 8*2048*20 int
    float* part = (float*)(idxb + (long)BB * Nn * KK);      // 8*1024*NCH f32
    float* ws1  = part + (long)BB * 1024 * NCH;             // 3*128
    float* ws2  = ws1 + 3 * 128;                            // 64*128
    float* ws3  = ws2 + 64 * 128;                           // 64*256
    float* ws4  = ws3 + 64 * 256;                           // 128*512
    __hip_bfloat16* Wgb = (__hip_bfloat16*)(ws4 + 128 * 512);   // 1024*512 bf16
    __hip_bfloat16* xbT = Wgb + (long)1024 * 512;               // 8*2048*512 bf16
    __hip_bfloat16* xbTlo = xbT + (long)BB * Nn * 512;          // 8*2048*512 bf16
    __hip_bfloat16* x1h = xbTlo + (long)BB * Nn * 512;          // 8*2048*32 bf16
    __hip_bfloat16* x1l = x1h + (long)BB * Nn * 32;             // 8*2048*32 bf16
    float* sq1  = (float*)(x1l + (long)BB * Nn * 32);           // 8*2048 f32
    float* sqv  = sq1 + (long)BB * Nn;                          // 8*2048 f32
    float* Z    = sqv + (long)BB * Nn;                          // 8*2048*512 f32

    const long XB = (long)512 * Nn;   // xcat batch stride
    const long TB = (long)Nn * 512;   // xbT batch stride (elems)

    wstack_kernel<<<(64 * 3 + 255) / 256, 256, 0, stream>>>(W1, ws1, 64, 3);
    wstack_kernel<<<(64 * 64 + 255) / 256, 256, 0, stream>>>(W2, ws2, 64, 64);
    wstack_kernel<<<(128 * 64 + 255) / 256, 256, 0, stream>>>(W3, ws3, 128, 64);
    wstack_kernel<<<(256 * 128 + 255) / 256, 256, 0, stream>>>(W4, ws4, 256, 128);
    tobf16_kernel<<<(1024 * 512 + 255) / 256, 256, 0, stream>>>(Wg, Wgb, 1024 * 512);
    split3_kernel<<<(BB * Nn) / 256, 256, 0, stream>>>(x, x1h, x1l, sq1);

    const int knn_grid = BB * (Nn / 8);    // 2048 blocks, 512 threads
    const int ep_grid  = (Nn / 16) * BB;   // 1024

    // stage 1: x (C=3, padded to K=32) -> xcat[0:64], xbT/xbTlo[:, 0:64), sqv
    knn_mfma<32><<<knn_grid, 512, 0, stream>>>(x1h, x1l, 32, (long)Nn * 32, 0, sq1, idxb);
    proj_gemm<3, 128><<<8 * 32 * 2, 256, 0, stream>>>(x, (long)3 * Nn, ws1, Z);
    gather_max<64, true><<<ep_grid, 256, 0, stream>>>(Z, idxb, xcat, XB, xbT, xbTlo, sqv, 0);
    // stage 2
    knn_mfma<64><<<knn_grid, 512, 0, stream>>>(xbT, xbTlo, 512, TB, 0, sqv, idxb);
    proj_gemm<64, 128><<<8 * 32 * 2, 256, 0, stream>>>(xcat, XB, ws2, Z);
    gather_max<64, true><<<ep_grid, 256, 0, stream>>>(Z, idxb, xcat + (long)64 * Nn, XB, xbT, xbTlo, sqv, 64);
    // stage 3
    knn_mfma<64><<<knn_grid, 512, 0, stream>>>(xbT, xbTlo, 512, TB, 64, sqv, idxb);
    proj_gemm<64, 256><<<8 * 32 * 4, 256, 0, stream>>>(xcat + (long)64 * Nn, XB, ws3, Z);
    gather_max<128, true><<<ep_grid, 256, 0, stream>>>(Z, idxb, xcat + (long)128 * Nn, XB, xbT, xbTlo, sqv, 128);
    // stage 4
    knn_mfma<128><<<knn_grid, 512, 0, stream>>>(xbT, xbTlo, 512, TB, 128, sqv, idxb);
    proj_gemm<128, 512><<<8 * 32 * 8, 256, 0, stream>>>(xcat + (long)128 * Nn, XB, ws4, Z);
    gather_max<256, false><<<ep_grid, 256, 0, stream>>>(Z, idxb, xcat + (long)256 * Nn, XB, xbT, xbTlo, sqv, 256);

    // global conv via MFMA (fused max) + final reduce
    global_mfma<<<BB * 16 * 8, 256, 0, stream>>>(Wgb, xbT, part);
    gmax_kernel<<<BB * 1024 / 256, 256, 0, stream>>>(part, out);
}

// Round 5
// 664.141 us; speedup vs baseline: 1.5620x; 1.5620x over previous
//
#include <hip/hip_runtime.h>
#include <hip/hip_bf16.h>
#include <cfloat>

#define Nn 2048
#define KK 20
#define BB 8
#define SLOPE 0.2f
#define NCH 32   // partial chunks in global conv (8 nblk x 4 waves)

typedef __bf16 bf16x8 __attribute__((ext_vector_type(8)));
typedef float f32x4 __attribute__((ext_vector_type(4)));

// ---------------- weight stack: Wstk[c][o] = W[o][c]; Wstk[c][Co+o] = W[o][C+c]-W[o][c]
__global__ void wstack_kernel(const float* __restrict__ W, float* __restrict__ Wstk,
                              int Co, int C) {
    int i = blockIdx.x * 256 + threadIdx.x;
    if (i < Co * C) {
        int o = i / C, c = i - o * C;
        float a = W[(long)o * 2 * C + c];
        float bb = W[(long)o * 2 * C + C + c];
        Wstk[(long)c * 2 * Co + o] = a;
        Wstk[(long)c * 2 * Co + Co + o] = bb - a;
    }
}

// ---------------- fp32 -> bf16 copy ----------------
__global__ void tobf16_kernel(const float* __restrict__ A, __hip_bfloat16* __restrict__ B,
                              int n) {
    int i = blockIdx.x * 256 + threadIdx.x;
    if (i < n) B[i] = __float2bfloat16(A[i]);
}

// order-preserving float-bits -> u32 map (works for negatives)
__device__ __forceinline__ unsigned fkey(float f) {
    unsigned u = __float_as_uint(f);
    return u ^ (((unsigned)((int)u >> 31)) | 0x80000000u);
}

// ---------------- KNN: 8 rows per block, 512 threads ----------------
// dist order == xx_j - 2*dot(x_n, x_j)  (per-row const xx_n dropped: order-invariant)
// Distance: thread owns contiguous j in [4*tid, 4*tid+4) -> float4 loads, uint4 LDS stores.
// Selection: per-lane top-2 -> u32 bitonic sort of 128-key union -> threshold T
// (union rank-19 >= true rank-19, so {key<=T} is a superset of the top-20 with
// count 20+e). Capture <=4 candidates/lane in registers; e==0 -> prefix emit;
// e>0 -> e wave-max removal rounds (exact, idx tie-break). Classic 20-round
// extraction only for the ~1e-5 overflow case.
template<int C>
__global__ void __launch_bounds__(512)
knn_kernel(const float* __restrict__ x, long bstride, int* __restrict__ idx) {
    __shared__ unsigned dist[8][Nn];   // XOR-mapped float keys; 64 KB exactly
    const int tid = threadIdx.x;
    const int b  = blockIdx.x >> 8;         // Nn/8 = 256 blocks per b
    const int n0 = (blockIdx.x & 255) * 8;
    const float* xb = x + (long)b * bstride;

    float acc[8][4];
    #pragma unroll
    for (int r = 0; r < 8; ++r)
        #pragma unroll
        for (int q = 0; q < 4; ++q) acc[r][q] = 0.f;
    float sq[4] = {0.f, 0.f, 0.f, 0.f};

    #pragma unroll 4
    for (int c = 0; c < C; ++c) {
        const float* xp = xb + (long)c * Nn;
        float4 xv = *(const float4*)(xp + tid * 4);
        float4 c0 = *(const float4*)(xp + n0);      // block-uniform -> scalar pipe
        float4 c1 = *(const float4*)(xp + n0 + 4);
        sq[0] += xv.x * xv.x; sq[1] += xv.y * xv.y; sq[2] += xv.z * xv.z; sq[3] += xv.w * xv.w;
        acc[0][0] += c0.x * xv.x; acc[0][1] += c0.x * xv.y; acc[0][2] += c0.x * xv.z; acc[0][3] += c0.x * xv.w;
        acc[1][0] += c0.y * xv.x; acc[1][1] += c0.y * xv.y; acc[1][2] += c0.y * xv.z; acc[1][3] += c0.y * xv.w;
        acc[2][0] += c0.z * xv.x; acc[2][1] += c0.z * xv.y; acc[2][2] += c0.z * xv.z; acc[2][3] += c0.z * xv.w;
        acc[3][0] += c0.w * xv.x; acc[3][1] += c0.w * xv.y; acc[3][2] += c0.w * xv.z; acc[3][3] += c0.w * xv.w;
        acc[4][0] += c1.x * xv.x; acc[4][1] += c1.x * xv.y; acc[4][2] += c1.x * xv.z; acc[4][3] += c1.x * xv.w;
        acc[5][0] += c1.y * xv.x; acc[5][1] += c1.y * xv.y; acc[5][2] += c1.y * xv.z; acc[5][3] += c1.y * xv.w;
        acc[6][0] += c1.z * xv.x; acc[6][1] += c1.z * xv.y; acc[6][2] += c1.z * xv.z; acc[6][3] += c1.z * xv.w;
        acc[7][0] += c1.w * xv.x; acc[7][1] += c1.w * xv.y; acc[7][2] += c1.w * xv.z; acc[7][3] += c1.w * xv.w;
    }
    #pragma unroll
    for (int r = 0; r < 8; ++r) {
        uint4 kv;
        kv.x = fkey(fmaf(-2.f, acc[r][0], sq[0]));
        kv.y = fkey(fmaf(-2.f, acc[r][1], sq[1]));
        kv.z = fkey(fmaf(-2.f, acc[r][2], sq[2]));
        kv.w = fkey(fmaf(-2.f, acc[r][3], sq[3]));
        *(uint4*)&dist[r][tid * 4] = kv;
    }
    __syncthreads();

    // selection: wave w owns row w
    const int w = tid >> 6, lane = tid & 63;
    unsigned* drow = dist[w];
    int* outp = idx + ((long)b * Nn + n0 + w) * KK;

    auto scan2 = [&](unsigned long long& m1, unsigned long long& m2) {
        m1 = ~0ull; m2 = ~0ull;
        #pragma unroll
        for (int jj = 0; jj < 8; ++jj) {
            int j4 = (jj * 64 + lane) * 4;
            uint4 v = *(const uint4*)(drow + j4);
            unsigned long long kk0 = ((unsigned long long)v.x << 32) | (unsigned)(j4 + 0);
            unsigned long long kk1 = ((unsigned long long)v.y << 32) | (unsigned)(j4 + 1);
            unsigned long long kk2 = ((unsigned long long)v.z << 32) | (unsigned)(j4 + 2);
            unsigned long long kk3 = ((unsigned long long)v.w << 32) | (unsigned)(j4 + 3);
            unsigned long long hi;
            hi = kk0 > m1 ? kk0 : m1; m1 = kk0 < m1 ? kk0 : m1; m2 = hi < m2 ? hi : m2;
            hi = kk1 > m1 ? kk1 : m1; m1 = kk1 < m1 ? kk1 : m1; m2 = hi < m2 ? hi : m2;
            hi = kk2 > m1 ? kk2 : m1; m1 = kk2 < m1 ? kk2 : m1; m2 = hi < m2 ? hi : m2;
            hi = kk3 > m1 ? kk3 : m1; m1 = kk3 < m1 ? kk3 : m1; m2 = hi < m2 ? hi : m2;
        }
    };

    unsigned long long lm1, lm2;
    scan2(lm1, lm2);

    // ---- u32 bitonic sort of the 128-key union (2 keys/lane, element e = 2*lane + s) ----
    unsigned T;
    {
        unsigned sa = (unsigned)(lm1 >> 32), sb = (unsigned)(lm2 >> 32);  // sa <= sb
        #pragma unroll
        for (int size = 2; size <= 128; size <<= 1) {
            #pragma unroll
            for (int str = size >> 1; str >= 2; str >>= 1) {
                const int h = str >> 1;                       // lane-xor distance
                const bool asc = (((lane << 1) & size) == 0);
                const bool keepmin = (((lane & h) == 0) == asc);
                unsigned pa = __shfl_xor(sa, h, 64);
                unsigned pb = __shfl_xor(sb, h, 64);
                sa = keepmin ? (sa < pa ? sa : pa) : (sa > pa ? sa : pa);
                sb = keepmin ? (sb < pb ? sb : pb) : (sb > pb ? sb : pb);
            }
            const bool asc = (((lane << 1) & size) == 0);
            unsigned mn = sa < sb ? sa : sb;
            unsigned mx = sa < sb ? sb : sa;
            sa = asc ? mn : mx; sb = asc ? mx : mn;
        }
        T = __shfl(sb, 9, 64);   // element 19 -> lane 9, odd slot
    }

    // ---- capture rescan: count all keys <= T, keep up to 4 (key|idx) per lane ----
    unsigned long long c0 = 0, c1 = 0, c2 = 0, c3 = 0;   // 0 = empty (real keys > 0)
    unsigned cnt = 0;
    #pragma unroll
    for (int jj = 0; jj < 8; ++jj) {
        int j4 = (jj * 64 + lane) * 4;
        uint4 v = *(const uint4*)(drow + j4);
        #pragma unroll
        for (int q = 0; q < 4; ++q) {
            unsigned kq = q == 0 ? v.x : q == 1 ? v.y : q == 2 ? v.z : v.w;
            if (kq <= T) {
                unsigned long long kv = ((unsigned long long)kq << 32) | (unsigned)(j4 + q);
                if (cnt == 0) c0 = kv;
                else if (cnt == 1) c1 = kv;
                else if (cnt == 2) c2 = kv;
                else if (cnt == 3) c3 = kv;
                ++cnt;
            }
        }
    }

    unsigned tot = cnt;
    #pragma unroll
    for (int s = 1; s < 64; s <<= 1) tot += __shfl_xor(tot, s, 64);
    unsigned long long anyovf = __ballot(cnt > 4);

    if (anyovf == 0 && tot <= 44) {
        // exact: remove the e = tot-20 largest candidates (u64 order = key, idx tie-break)
        int e = (int)tot - KK;
        for (int rr = 0; rr < e; ++rr) {
            unsigned long long mymax = c0;
            if (c1 > mymax) mymax = c1;
            if (c2 > mymax) mymax = c2;
            if (c3 > mymax) mymax = c3;
            unsigned long long wm = mymax;
            #pragma unroll
            for (int s = 1; s < 64; s <<= 1) {
                unsigned long long o = __shfl_xor(wm, s, 64);
                wm = o > wm ? o : wm;
            }
            if (mymax == wm) {           // unique winner (idx makes u64 unique)
                if (c3 == wm) c3 = 0;
                else if (c2 == wm) c2 = 0;
                else if (c1 == wm) c1 = 0;
                else c0 = 0;
            }
        }
        unsigned myc = (c0 != 0) + (c1 != 0) + (c2 != 0) + (c3 != 0);
        unsigned inc = myc;
        #pragma unroll
        for (int off = 1; off < 64; off <<= 1) {
            unsigned t2 = __shfl_up(inc, off, 64);
            if (lane >= off) inc += t2;
        }
        int p = (int)(inc - myc);
        if (c0 != 0) outp[p++] = (int)(unsigned)c0;
        if (c1 != 0) outp[p++] = (int)(unsigned)c1;
        if (c2 != 0) outp[p++] = (int)(unsigned)c2;
        if (c3 != 0) outp[p++] = (int)(unsigned)c3;
        return;   // wave-uniform exit (no barriers follow)
    }

    // ---- ultra-rare classic extraction (lane held >4 candidates or e too big) ----
    for (int k = 0; k < KK; ++k) {
        unsigned key = (unsigned)(lm1 >> 32);
        unsigned bk = key;
        #pragma unroll
        for (int s = 1; s < 64; s <<= 1) {
            unsigned ob = __shfl_xor(bk, s, 64);
            bk = ob < bk ? ob : bk;
        }
        unsigned long long winners = __ballot(key == bk);
        int wl = (int)(__ffsll((unsigned long long)winners) - 1);
        int bi = (int)__shfl((unsigned)lm1, wl, 64);   // winner's j (low 32 bits)
        if (lane == 0) outp[k] = bi;
        if (lane == wl) {
            drow[bi] = 0xFFFFFFFFu;  // consumed sentinel (keeps refills correct)
            if (lm2 != ~0ull) { lm1 = lm2; lm2 = ~0ull; }
            else scan2(lm1, lm2);    // rare: lane's 3rd+ win since last refill
        }
    }
}

// ---------------- projection GEMM: Z[m][0..2Co) = sum_c x[c][m] * Wstk[c][.] ----
template<int CIN, int CO2>
__global__ void __launch_bounds__(256)
proj_gemm(const float* __restrict__ x, long bst,
          const float* __restrict__ Wstk, float* __restrict__ Z) {
    const int tid = threadIdx.x;
    const int b  = blockIdx.x & 7;
    const int mt = (blockIdx.x >> 3) & 31;
    const int ot = blockIdx.x >> 8;
    const int mi = mt * 64 + (tid & 15) * 4;
    const int oj = ot * 64 + (tid >> 4) * 4;
    const float* xb = x + (long)b * bst + mi;

    float acc[4][4];
    #pragma unroll
    for (int r = 0; r < 4; ++r)
        #pragma unroll
        for (int j = 0; j < 4; ++j) acc[r][j] = 0.f;

    #pragma unroll 4
    for (int c = 0; c < CIN; ++c) {
        float4 xv = *(const float4*)(xb + (long)c * Nn);
        float4 wv = *(const float4*)(Wstk + (long)c * CO2 + oj);
        acc[0][0] += xv.x * wv.x; acc[0][1] += xv.x * wv.y; acc[0][2] += xv.x * wv.z; acc[0][3] += xv.x * wv.w;
        acc[1][0] += xv.y * wv.x; acc[1][1] += xv.y * wv.y; acc[1][2] += xv.y * wv.z; acc[1][3] += xv.y * wv.w;
        acc[2][0] += xv.z * wv.x; acc[2][1] += xv.z * wv.y; acc[2][2] += xv.z * wv.z; acc[2][3] += xv.z * wv.w;
        acc[3][0] += xv.w * wv.x; acc[3][1] += xv.w * wv.y; acc[3][2] += xv.w * wv.z; acc[3][3] += xv.w * wv.w;
    }
    float* Zb = Z + (long)b * 2048 * CO2;
    #pragma unroll
    for (int r = 0; r < 4; ++r) {
        float4 v = make_float4(acc[r][0], acc[r][1], acc[r][2], acc[r][3]);
        *(float4*)(Zb + (long)(mi + r) * CO2 + oj) = v;
    }
}

// ---------------- gather-max epilogue (also emits bf16 n-major copy) ----------------
template<int CO>
__global__ void __launch_bounds__(256)
gather_max(const float* __restrict__ Z, const int* __restrict__ idx,
           float* __restrict__ out, long obst,
           __hip_bfloat16* __restrict__ xbT, int coff) {
    constexpr int CO2 = 2 * CO;
    constexpr int VEC = CO / 64;
    __shared__ float tile[16][CO + 4];
    __shared__ int ji[16][KK];
    const int tid = threadIdx.x;
    const int b  = blockIdx.x & 7;
    const int n0 = (blockIdx.x >> 3) * 16;
    const float* Zb = Z + (long)b * 2048 * CO2;

    for (int t = tid; t < 16 * KK; t += 256) {
        int nn = t / KK, k = t - nn * KK;
        ji[nn][k] = idx[((long)b * Nn + n0 + nn) * KK + k];
    }
    __syncthreads();

    const int w = tid >> 6, lane = tid & 63;
    for (int i = 0; i < 4; ++i) {
        int nl = w * 4 + i, n = n0 + nl;
        float mx[VEC];
        #pragma unroll
        for (int v = 0; v < VEC; ++v) mx[v] = -FLT_MAX;
        for (int k = 0; k < KK; ++k) {
            int m = ji[nl][k];
            const float* zr = Zb + (long)m * CO2 + lane * VEC;
            if constexpr (VEC == 4) {
                float4 zv = *(const float4*)zr;
                mx[0] = fmaxf(mx[0], zv.x); mx[1] = fmaxf(mx[1], zv.y);
                mx[2] = fmaxf(mx[2], zv.z); mx[3] = fmaxf(mx[3], zv.w);
            } else if constexpr (VEC == 2) {
                float2 zv = *(const float2*)zr;
                mx[0] = fmaxf(mx[0], zv.x); mx[1] = fmaxf(mx[1], zv.y);
            } else {
                mx[0] = fmaxf(mx[0], zr[0]);
            }
        }
        const float* zc = Zb + (long)n * CO2 + CO + lane * VEC;
        __hip_bfloat16* xr = xbT + ((long)b * 2048 + n) * 512 + coff + lane * VEC;
        float y[VEC];
        if constexpr (VEC == 4) {
            float4 cv = *(const float4*)zc;
            y[0] = mx[0] + cv.x; y[1] = mx[1] + cv.y; y[2] = mx[2] + cv.z; y[3] = mx[3] + cv.w;
        } else if constexpr (VEC == 2) {
            float2 cv = *(const float2*)zc;
            y[0] = mx[0] + cv.x; y[1] = mx[1] + cv.y;
        } else {
            y[0] = mx[0] + zc[0];
        }
        unsigned short hb[VEC];
        #pragma unroll
        for (int v = 0; v < VEC; ++v) {
            y[v] = y[v] > 0.f ? y[v] : SLOPE * y[v];
            tile[nl][lane * VEC + v] = y[v];
            __hip_bfloat16 h = __float2bfloat16(y[v]);
            hb[v] = *(unsigned short*)&h;
        }
        if constexpr (VEC == 4) {
            ushort4 pk; pk.x = hb[0]; pk.y = hb[1]; pk.z = hb[2]; pk.w = hb[3];
            *(ushort4*)xr = pk;
        } else if constexpr (VEC == 2) {
            ushort2 pk; pk.x = hb[0]; pk.y = hb[1];
            *(ushort2*)xr = pk;
        } else {
            *(unsigned short*)xr = hb[0];
        }
    }
    __syncthreads();

    for (int r = tid; r < CO * 4; r += 256) {
        int o = r >> 2, q = r & 3;
        float4 vv;
        vv.x = tile[q * 4 + 0][o];
        vv.y = tile[q * 4 + 1][o];
        vv.z = tile[q * 4 + 2][o];
        vv.w = tile[q * 4 + 3][o];
        *(float4*)(out + (long)b * obst + (long)o * Nn + n0 + q * 4) = vv;
    }
}

// ---------------- Global conv via bf16 MFMA, fused max-over-n ----------------
__global__ void __launch_bounds__(256)
global_mfma(const __hip_bfloat16* __restrict__ Wgb,   // [1024][512]
            const __hip_bfloat16* __restrict__ xbT,   // [B][2048][512]
            float* __restrict__ partial) {            // [B][1024][NCH]
    const int tid = threadIdx.x;
    const int w = tid >> 6, lane = tid & 63;
    const int lm = lane & 15, quad = lane >> 4;
    const int b  = blockIdx.x >> 7;
    const int ot = (blockIdx.x >> 3) & 15;
    const int nb = blockIdx.x & 7;
    const int o0 = ot * 64;
    const int nbw = nb * 256 + w * 64;

    const __hip_bfloat16* Arow = Wgb + (long)(o0 + lm) * 512 + quad * 8;
    const __hip_bfloat16* Brow = xbT + ((long)b * 2048 + nbw + lm) * 512 + quad * 8;

    f32x4 acc[4][4];
    #pragma unroll
    for (int mt = 0; mt < 4; ++mt)
        #pragma unroll
        for (int nt = 0; nt < 4; ++nt)
            acc[mt][nt] = (f32x4){0.f, 0.f, 0.f, 0.f};

    #pragma unroll 2
    for (int kk = 0; kk < 512; kk += 32) {
        bf16x8 a[4], bb[4];
        #pragma unroll
        for (int mt = 0; mt < 4; ++mt)
            a[mt] = *(const bf16x8*)(const void*)(Arow + (long)mt * 16 * 512 + kk);
        #pragma unroll
        for (int nt = 0; nt < 4; ++nt)
            bb[nt] = *(const bf16x8*)(const void*)(Brow + (long)nt * 16 * 512 + kk);
        #pragma unroll
        for (int mt = 0; mt < 4; ++mt)
            #pragma unroll
            for (int nt = 0; nt < 4; ++nt)
                acc[mt][nt] = __builtin_amdgcn_mfma_f32_16x16x32_bf16(
                    a[mt], bb[nt], acc[mt][nt], 0, 0, 0);
    }

    // D mapping: col(n) = lane&15, row(m) = quad*4 + reg
    #pragma unroll
    for (int mt = 0; mt < 4; ++mt) {
        #pragma unroll
        for (int r = 0; r < 4; ++r) {
            float v = fmaxf(fmaxf(acc[mt][0][r], acc[mt][1][r]),
                            fmaxf(acc[mt][2][r], acc[mt][3][r]));
            #pragma unroll
            for (int s = 1; s < 16; s <<= 1)
                v = fmaxf(v, __shfl_xor(v, s, 16));
            if (lm == 0) {
                int o = o0 + mt * 16 + quad * 4 + r;
                partial[((long)b * 1024 + o) * NCH + nb * 4 + w] = v;
            }
        }
    }
}

// ---------------- final max over chunks + leaky ----------------
__global__ void gmax_kernel(const float* __restrict__ partial, float* __restrict__ out) {
    int i = blockIdx.x * 256 + threadIdx.x;   // 0..8191
    float m = -FLT_MAX;
    #pragma unroll
    for (int j = 0; j < NCH; ++j) m = fmaxf(m, partial[(long)i * NCH + j]);
    out[i] = m > 0.f ? m : SLOPE * m;
}

extern "C" void kernel_launch(void* const* d_in, const int* in_sizes, int n_in,
                              void* d_out, int out_size, void* d_ws, size_t ws_size,
                              hipStream_t stream) {
    const float* x  = (const float*)d_in[0];
    const float* W1 = (const float*)d_in[1];   // [64][6]
    const float* W2 = (const float*)d_in[2];   // [64][128]
    const float* W3 = (const float*)d_in[3];   // [128][128]
    const float* W4 = (const float*)d_in[4];   // [256][256]
    const float* Wg = (const float*)d_in[5];   // [1024][512]
    float* out = (float*)d_out;

    float* ws = (float*)d_ws;
    float* xcat = ws;                                       // 8*512*2048 f32
    int*   idxb = (int*)(xcat + (long)BB * 512 * Nn);       // 8*2048*20 int
    float* part = (float*)(idxb + (long)BB * Nn * KK);      // 8*1024*NCH f32
    float* ws1  = part + (long)BB * 1024 * NCH;             // 3*128
    float* ws2  = ws1 + 3 * 128;                            // 64*128
    float* ws3  = ws2 + 64 * 128;                           // 64*256
    float* ws4  = ws3 + 64 * 256;                           // 128*512
    __hip_bfloat16* Wgb = (__hip_bfloat16*)(ws4 + 128 * 512);   // 1024*512 bf16
    __hip_bfloat16* xbT = Wgb + (long)1024 * 512;               // 8*2048*512 bf16
    float* Z    = (float*)(xbT + (long)BB * Nn * 512);          // 8*2048*512 f32

    const long XB = (long)512 * Nn;   // xcat batch stride

    wstack_kernel<<<(64 * 3 + 255) / 256, 256, 0, stream>>>(W1, ws1, 64, 3);
    wstack_kernel<<<(64 * 64 + 255) / 256, 256, 0, stream>>>(W2, ws2, 64, 64);
    wstack_kernel<<<(128 * 64 + 255) / 256, 256, 0, stream>>>(W3, ws3, 128, 64);
    wstack_kernel<<<(256 * 128 + 255) / 256, 256, 0, stream>>>(W4, ws4, 256, 128);
    tobf16_kernel<<<(1024 * 512 + 255) / 256, 256, 0, stream>>>(Wg, Wgb, 1024 * 512);

    const int knn_grid = BB * (Nn / 8);    // 2048 blocks, 512 threads
    const int ep_grid  = (Nn / 16) * BB;   // 1024

    // stage 1: x (C=3) -> xcat[0:64], xbT[:, 0:64)
    knn_kernel<3><<<knn_grid, 512, 0, stream>>>(x, (long)3 * Nn, idxb);
    proj_gemm<3, 128><<<8 * 32 * 2, 256, 0, stream>>>(x, (long)3 * Nn, ws1, Z);
    gather_max<64><<<ep_grid, 256, 0, stream>>>(Z, idxb, xcat, XB, xbT, 0);
    // stage 2
    knn_kernel<64><<<knn_grid, 512, 0, stream>>>(xcat, XB, idxb);
    proj_gemm<64, 128><<<8 * 32 * 2, 256, 0, stream>>>(xcat, XB, ws2, Z);
    gather_max<64><<<ep_grid, 256, 0, stream>>>(Z, idxb, xcat + (long)64 * Nn, XB, xbT, 64);
    // stage 3
    knn_kernel<64><<<knn_grid, 512, 0, stream>>>(xcat + (long)64 * Nn, XB, idxb);
    proj_gemm<64, 256><<<8 * 32 * 4, 256, 0, stream>>>(xcat + (long)64 * Nn, XB, ws3, Z);
    gather_max<128><<<ep_grid, 256, 0, stream>>>(Z, idxb, xcat + (long)128 * Nn, XB, xbT, 128);
    // stage 4
    knn_kernel<128><<<knn_grid, 512, 0, stream>>>(xcat + (long)128 * Nn, XB, idxb);
    proj_gemm<128, 512><<<8 * 32 * 8, 256, 0, stream>>>(xcat + (long)128 * Nn, XB, ws4, Z);
    gather_max<256><<<ep_grid, 256, 0, stream>>>(Z, idxb, xcat + (long)256 * Nn, XB, xbT, 256);

    // global conv via MFMA (fused max) + final reduce
    global_mfma<<<BB * 16 * 8, 256, 0, stream>>>(Wgb, xbT, part);
    gmax_kernel<<<BB * 1024 / 256, 256, 0, stream>>>(part, out);
}